// Round 7
// baseline (516.616 us; speedup 1.0000x reference)
//
#include <hip/hip_runtime.h>
#include <math.h>

#define N_NODES 50000
#define E_EDGES 1600000
#define IN_F    128
#define OUT_F   64
#define OMEGA   0.1f
#define NIDX    5000
#define NB2     1563       // ceil(50000/32) buckets of 32 nodes
#define CAPG    1536       // fixed bucket capacity (mean 1024, +16 sigma)

#define GRID_H  782        // node_h sub-blocks (64 rows each)
#define GRID_G  64         // gamma sub-blocks (4 degrees each, wave-per-degree)
#define GRID_B  512        // bin sub-blocks (grid-stride over edges)
#define GRID_M  20         // mult/degsum sub-blocks
#define GRID_A  (GRID_H + GRID_G + GRID_B + GRID_M)

typedef __attribute__((ext_vector_type(8))) short short8_t;
typedef __attribute__((ext_vector_type(4))) float f32x4;

__device__ __forceinline__ float lrelu(float x) { return x > 0.f ? x : 0.01f * x; }

__device__ __forceinline__ unsigned short f2bf(float f) {
    unsigned u = __float_as_uint(f);
    return (unsigned short)((u + 0x7FFFu + ((u >> 16) & 1u)) >> 16);
}
__device__ __forceinline__ float bf2f(unsigned short v) {
    return __uint_as_float((unsigned)v << 16);
}

// ============ K_pre: union of {node_h | gamma | bin | mult+degsum} ==========
__global__ __launch_bounds__(256) void k_pre(
    const float* __restrict__ x, const float* __restrict__ W,
    const float* __restrict__ b, const float* __restrict__ a,
    const float* __restrict__ PE, const float* __restrict__ Wg,
    const float* __restrict__ Wb, const float* __restrict__ bg,
    const float* __restrict__ bb,
    const int* __restrict__ edge, const int* __restrict__ degree,
    const int* __restrict__ idx,
    unsigned short* __restrict__ h, float* __restrict__ s, float* __restrict__ t,
    float2* __restrict__ gb2, float* __restrict__ gnorm, float* __restrict__ bnorm,
    int* __restrict__ gcursor, unsigned* __restrict__ binned,
    int* __restrict__ degsum, int* __restrict__ mult)
{
    __shared__ unsigned short xs[64 * 136];    // only node_h branch uses LDS
    const int blk = blockIdx.x;
    const int tid = threadIdx.x;
    const int lane = tid & 63, w = tid >> 6;

    if (blk < GRID_H) {
        // ---------------- node_h: h = (x@W^T + b)*8 (bf16); s,t -------------
        const int l15 = lane & 15, l4 = lane >> 4;
        const int row0 = blk * 64;

        short8_t bw_[4][4];
        #pragma unroll
        for (int nt = 0; nt < 4; ++nt) {
            #pragma unroll
            for (int ks = 0; ks < 4; ++ks) {
                const float* wp = &W[(nt * 16 + l15) * 128 + ks * 32 + l4 * 8];
                const float4 w0 = *(const float4*)wp;
                const float4 w1 = *(const float4*)(wp + 4);
                short8_t v;
                v[0] = (short)f2bf(w0.x); v[1] = (short)f2bf(w0.y);
                v[2] = (short)f2bf(w0.z); v[3] = (short)f2bf(w0.w);
                v[4] = (short)f2bf(w1.x); v[5] = (short)f2bf(w1.y);
                v[6] = (short)f2bf(w1.z); v[7] = (short)f2bf(w1.w);
                bw_[nt][ks] = v;
            }
        }
        float bcol[4], acol[4], acol2[4];
        #pragma unroll
        for (int nt = 0; nt < 4; ++nt) {
            bcol[nt]  = b[nt * 16 + l15];
            acol[nt]  = a[nt * 16 + l15];
            acol2[nt] = a[64 + nt * 16 + l15];
        }

        for (int f = tid; f < 2048; f += 256) {
            const int row = f >> 5, c4 = f & 31;
            const int rsrc = min(row0 + row, N_NODES - 1);
            const float4 v = *(const float4*)&x[(size_t)rsrc * IN_F + c4 * 4];
            ushort4 u;
            u.x = f2bf(v.x); u.y = f2bf(v.y); u.z = f2bf(v.z); u.w = f2bf(v.w);
            *(ushort4*)&xs[row * 136 + c4 * 4] = u;
        }
        __syncthreads();

        short8_t av[4];
        #pragma unroll
        for (int ks = 0; ks < 4; ++ks)
            av[ks] = *(const short8_t*)&xs[(w * 16 + l15) * 136 + ks * 32 + l4 * 8];

        f32x4 acc[4];
        #pragma unroll
        for (int nt = 0; nt < 4; ++nt) { acc[nt][0]=0.f; acc[nt][1]=0.f; acc[nt][2]=0.f; acc[nt][3]=0.f; }
        #pragma unroll
        for (int nt = 0; nt < 4; ++nt)
            #pragma unroll
            for (int ks = 0; ks < 4; ++ks)
                acc[nt] = __builtin_amdgcn_mfma_f32_16x16x32_bf16(av[ks], bw_[nt][ks], acc[nt], 0, 0, 0);

        float sp[4] = {0.f,0.f,0.f,0.f}, tp[4] = {0.f,0.f,0.f,0.f};
        #pragma unroll
        for (int nt = 0; nt < 4; ++nt) {
            #pragma unroll
            for (int reg = 0; reg < 4; ++reg) {
                const float hv = (acc[nt][reg] + bcol[nt]) * 8.0f;
                const int row = row0 + w * 16 + l4 * 4 + reg;
                if (row < N_NODES) h[(size_t)row * OUT_F + nt * 16 + l15] = f2bf(hv);
                sp[reg] = fmaf(hv, acol[nt],  sp[reg]);
                tp[reg] = fmaf(hv, acol2[nt], tp[reg]);
            }
        }
        #pragma unroll
        for (int reg = 0; reg < 4; ++reg) {
            float sv = sp[reg], tv = tp[reg];
            for (int m = 1; m < 16; m <<= 1) {
                sv += __shfl_xor(sv, m, 64);
                tv += __shfl_xor(tv, m, 64);
            }
            const int row = row0 + w * 16 + l4 * 4 + reg;
            if (l15 == 0 && row < N_NODES) { s[row] = sv; t[row] = tv; }
        }
    } else if (blk < GRID_H + GRID_G) {
        // ---------------- gamma/beta + norm tables (wave per degree) --------
        const int d = (blk - GRID_H) * 4 + w;
        const int o = lane;
        float ga = bg[o], be = bb[o];
        #pragma unroll 8
        for (int k = 0; k < 64; ++k) {
            const float m = PE[d * 64 + k];
            ga = fmaf(m, Wg[k * 64 + o], ga);
            be = fmaf(m, Wb[k * 64 + o], be);
        }
        ga = lrelu(ga); be = lrelu(be);
        gb2[d * 64 + o] = make_float2(ga, be);
        float g2 = ga * ga, b2 = be * be;
        for (int m2 = 32; m2; m2 >>= 1) {
            g2 += __shfl_down(g2, m2, 64);
            b2 += __shfl_down(b2, m2, 64);
        }
        if (o == 0) { gnorm[d] = sqrtf(g2); bnorm[d] = sqrtf(b2); }
    } else if (blk < GRID_H + GRID_G + GRID_B) {
        // ---------------- bin: single-pass bucket scatter --------------------
        const int b0 = blk - GRID_H - GRID_G;
        for (int e = b0 * 256 + tid; e < E_EDGES; e += GRID_B * 256) {
            const int sv = edge[e];
            const int dvv = edge[E_EDGES + e];
            const int bk = sv >> 5;
            const int pos = atomicAdd(&gcursor[bk], 1);
            if (pos < CAPG)
                binned[(size_t)bk * CAPG + pos] = ((unsigned)(sv & 31) << 16) | (unsigned)dvv;
        }
    } else {
        // ---------------- mult histogram + degree sum ------------------------
        const int b0 = blk - GRID_H - GRID_G - GRID_B;
        const int stride = GRID_M * 256;
        for (int i2 = b0 * 256 + tid; i2 < NIDX; i2 += stride)
            atomicAdd(&mult[idx[i2]], 1);
        int dvs = 0;
        for (int i2 = b0 * 256 + tid; i2 < N_NODES; i2 += stride)
            dvs += degree[i2];
        for (int off = 32; off; off >>= 1) dvs += __shfl_down(dvs, off, 64);
        if (lane == 0 && dvs) atomicAdd(degsum, dvs);
    }
}

// ============ k_mega: sort-in-LDS + gather + MFMA epilogue + fused loss =====
__global__ __launch_bounds__(256, 4) void k_mega(
    const unsigned* __restrict__ binned, const int* __restrict__ gcursor,
    const unsigned short* __restrict__ h, const float* __restrict__ s,
    const float* __restrict__ t, const int* __restrict__ degree,
    const int* __restrict__ degsum,
    const float* __restrict__ Wadd, const float* __restrict__ Wrev,
    const float2* __restrict__ gb2,
    const int* __restrict__ mult, const float* __restrict__ gnorm,
    const float* __restrict__ bnorm,
    float* __restrict__ out, float* __restrict__ lacc,
    unsigned* __restrict__ donecnt)
{
    __shared__ unsigned srt[CAPG];            // sorted (dst | ee_bf16<<16)
    __shared__ unsigned short si16[32 * 72];  // i in bf16, stride 72
    __shared__ float hp_l[32 * 68];           // hp f32, stride 68
    __shared__ float rs_l[32], sv_l[32];
    __shared__ int deg_l[32], cnt[32], curs[32], nbs[33];

    const int tid = threadIdx.x;
    const int lane = tid & 63, w = tid >> 6;
    const int l15 = lane & 15, l4 = lane >> 4;
    const int mat = w >> 1, rt = w & 1;       // wave role: matrix, row-tile
    const int bkt = blockIdx.x, n0 = bkt * 32;

    // B-fragments of this wave's weight matrix (held in regs the whole kernel)
    const float* __restrict__ Wsel = mat ? Wrev : Wadd;
    short8_t bfr[4][2];
    #pragma unroll
    for (int nt = 0; nt < 4; ++nt) {
        #pragma unroll
        for (int ks = 0; ks < 2; ++ks) {
            const float* wp = &Wsel[(nt * 16 + l15) * 64 + ks * 32 + l4 * 8];
            const float4 w0 = *(const float4*)wp;
            const float4 w1 = *(const float4*)(wp + 4);
            short8_t v;
            v[0] = (short)f2bf(w0.x); v[1] = (short)f2bf(w0.y);
            v[2] = (short)f2bf(w0.z); v[3] = (short)f2bf(w0.w);
            v[4] = (short)f2bf(w1.x); v[5] = (short)f2bf(w1.y);
            v[6] = (short)f2bf(w1.z); v[7] = (short)f2bf(w1.w);
            bfr[nt][ks] = v;
        }
    }

    if (tid < 32) {
        cnt[tid] = 0;
        const int nd = n0 + tid;
        sv_l[tid]  = (nd < N_NODES) ? s[nd] : 0.f;
        deg_l[tid] = (nd < N_NODES) ? degree[nd] : 0;
    }
    __syncthreads();

    const int cntE = min(gcursor[bkt], CAPG);
    const size_t bb = (size_t)bkt * CAPG;

    // pass 1: per-node histogram
    for (int j = tid; j < cntE; j += 256)
        atomicAdd(&cnt[binned[bb + j] >> 16], 1);
    __syncthreads();
    if (tid < 32) {
        const int v = cnt[tid];
        int val = v;
        #pragma unroll
        for (int m = 1; m < 32; m <<= 1) {
            const int o = __shfl_up(val, m, 64);
            if (tid >= m) val += o;
        }
        nbs[tid] = val - v;
        curs[tid] = val - v;
        if (tid == 31) nbs[32] = val;
    }
    __syncthreads();
    // pass 2: ee + counting-sort into LDS
    for (int j = tid; j < cntE; j += 256) {
        const unsigned en = binned[bb + j];
        const int sl = en >> 16;
        const int dvv = en & 0xFFFF;
        const float z = sv_l[sl] + t[dvv];
        const float ee = __expf(-(z > 0.f ? z : 0.01f * z));
        const int p = atomicAdd(&curs[sl], 1);
        srt[p] = (unsigned)dvv | ((unsigned)f2bf(ee) << 16);
    }
    __syncthreads();

    // gather: wave w -> nodes w, w+4, ...; 8-edge-parallel 8-lane groups
    const int g = lane >> 3, ql = lane & 7;
    for (int nl = w; nl < 32; nl += 4) {
        const int rb = nbs[nl], re = nbs[nl + 1];
        float ag[8] = {0.f,0.f,0.f,0.f,0.f,0.f,0.f,0.f};
        float pp[8] = {0.f,0.f,0.f,0.f,0.f,0.f,0.f,0.f};
        float er = 0.f;
        #pragma unroll 2
        for (int st = rb; st < re; st += 8) {
            const int j = st + g;
            if (j < re) {
                const unsigned en = srt[j];
                const float ee = bf2f((unsigned short)(en >> 16));
                const int dvv = en & 0xFFFF;
                const short8_t hv = *(const short8_t*)(h + (size_t)dvv * OUT_F + ql * 8);
                er += ee;
                #pragma unroll
                for (int c = 0; c < 8; ++c) {
                    const float f = bf2f((unsigned short)hv[c]);
                    ag[c] += f;
                    pp[c] = fmaf(ee, f, pp[c]);
                }
            }
        }
        #pragma unroll
        for (int c = 0; c < 8; ++c) {
            ag[c] += __shfl_xor(ag[c], 8, 64);
            ag[c] += __shfl_xor(ag[c], 16, 64);
            ag[c] += __shfl_xor(ag[c], 32, 64);
            pp[c] += __shfl_xor(pp[c], 8, 64);
            pp[c] += __shfl_xor(pp[c], 16, 64);
            pp[c] += __shfl_xor(pp[c], 32, 64);
        }
        er += __shfl_xor(er, 8, 64);
        er += __shfl_xor(er, 16, 64);
        er += __shfl_xor(er, 32, 64);
        if (lane == 0) rs_l[nl] = er;
        if (lane < 8) {
            const int dg = deg_l[nl];
            const float inv = (dg > 0) ? 1.f / (float)dg : 0.f;
            short8_t iv;
            #pragma unroll
            for (int c = 0; c < 8; ++c) iv[c] = (short)f2bf(ag[c] * inv);
            *(short8_t*)&si16[nl * 72 + lane * 8] = iv;
            float4 h0; h0.x = pp[0]; h0.y = pp[1]; h0.z = pp[2]; h0.w = pp[3];
            float4 h1; h1.x = pp[4]; h1.y = pp[5]; h1.z = pp[6]; h1.w = pp[7];
            *(float4*)&hp_l[nl * 68 + lane * 8]     = h0;
            *(float4*)&hp_l[nl * 68 + lane * 8 + 4] = h1;
        }
    }
    __syncthreads();

    // MFMA: b_sel = i @ Wsel^T for this wave's 16 rows
    short8_t av[2];
    #pragma unroll
    for (int ks = 0; ks < 2; ++ks)
        av[ks] = *(const short8_t*)&si16[(rt * 16 + l15) * 72 + ks * 32 + l4 * 8];
    f32x4 acc[4];
    #pragma unroll
    for (int nt = 0; nt < 4; ++nt) { acc[nt][0]=0.f; acc[nt][1]=0.f; acc[nt][2]=0.f; acc[nt][3]=0.f; }
    #pragma unroll
    for (int nt = 0; nt < 4; ++nt)
        #pragma unroll
        for (int ks = 0; ks < 2; ++ks)
            acc[nt] = __builtin_amdgcn_mfma_f32_16x16x32_bf16(av[ks], bfr[nt][ks], acc[nt], 0, 0, 0);

    const float kthr = (float)(*degsum) / (float)N_NODES;   // K_MULT = 1

    float lbacc = 0.f, lfacc = 0.f;
    #pragma unroll
    for (int reg = 0; reg < 4; ++reg) {
        const int nl = rt * 16 + l4 * 4 + reg;
        const int node = n0 + nl;
        const bool valid = node < N_NODES;
        const int dg = deg_l[nl];
        const bool rfl = ((float)dg < kthr);           // R == 1
        const bool sel = (rfl == (mat == 0)) && valid; // this wave's matrix selected
        const float rdenom = 1.f / (rs_l[nl] + 1e-5f + 1.f);
        const float sgn = (mat == 0) ? OMEGA : -OMEGA;
        float sq = 0.f;
        #pragma unroll
        for (int nt = 0; nt < 4; ++nt) {
            const int o = nt * 16 + l15;
            const float ad = acc[nt][reg];
            const float2 gb = gb2[dg * 64 + o];
            const float bs = fmaf(gb.x + 1.f, ad, gb.y);
            sq = fmaf(bs, bs, sq);
            if (sel) {
                float ov = (hp_l[nl * 68 + o] + sgn * bs) * rdenom;
                ov = ov > 0.f ? ov : 0.01f * ov;
                out[(size_t)node * OUT_F + o] = ov;
            }
        }
        sq += __shfl_xor(sq, 1, 64);
        sq += __shfl_xor(sq, 2, 64);
        sq += __shfl_xor(sq, 4, 64);
        sq += __shfl_xor(sq, 8, 64);
        if (l15 == 0 && sel) {
            const int mlt = mult[node];
            if (mlt) {
                lbacc += (float)mlt * sqrtf(sq);
                lfacc += (float)mlt * (gnorm[dg] + bnorm[dg]);
            }
        }
    }
    // reduce loss contributions across the 4 l15==0 lanes of this wave
    lbacc += __shfl_xor(lbacc, 16, 64);
    lbacc += __shfl_xor(lbacc, 32, 64);
    lfacc += __shfl_xor(lfacc, 16, 64);
    lfacc += __shfl_xor(lfacc, 32, 64);
    if (lane == 0 && (lbacc != 0.f || lfacc != 0.f)) {
        atomicAdd(&lacc[0], lbacc);
        atomicAdd(&lacc[1], lfacc);
    }
    __syncthreads();
    if (tid == 0) {
        __threadfence();
        const unsigned prev = atomicAdd(donecnt, 1u);
        if (prev == (unsigned)gridDim.x - 1) {
            const float tb = atomicAdd(&lacc[0], 0.f);
            const float tf = atomicAdd(&lacc[1], 0.f);
            out[(size_t)N_NODES * OUT_F]     = tb / (float)NIDX;
            out[(size_t)N_NODES * OUT_F + 1] = tf / (float)NIDX;
        }
    }
}

extern "C" void kernel_launch(void* const* d_in, const int* in_sizes, int n_in,
                              void* d_out, int out_size, void* d_ws, size_t ws_size,
                              hipStream_t stream)
{
    const float* x    = (const float*)d_in[0];
    const float* W    = (const float*)d_in[1];
    const float* b    = (const float*)d_in[2];
    const float* a    = (const float*)d_in[3];
    const float* Wg   = (const float*)d_in[4];
    const float* Wb   = (const float*)d_in[5];
    const float* bg   = (const float*)d_in[6];
    const float* bb   = (const float*)d_in[7];
    const float* Wadd = (const float*)d_in[8];
    const float* Wrev = (const float*)d_in[9];
    const float* PE   = (const float*)d_in[10];
    const int*  edge   = (const int*)d_in[11];
    const int*  degree = (const int*)d_in[12];
    const int*  idx    = (const int*)d_in[13];
    float* out = (float*)d_out;

    // ---- workspace layout: all zero-init arrays FIRST (one memset) ----
    float* ws = (float*)d_ws;
    size_t woff = 0;
    #define ALLOC(nwords) (ws + woff); woff += (((size_t)(nwords)) + 3) & ~(size_t)3;
    const size_t NF = (size_t)N_NODES * OUT_F;
    int*   gcursor = (int*)ALLOC(NB2);             // [zeroed]
    int*   degsum  = (int*)ALLOC(4);               // [zeroed]
    float* lacc    = ALLOC(4);                     // [zeroed]
    unsigned* donecnt = (unsigned*)ALLOC(4);       // [zeroed]
    int*   mult    = (int*)ALLOC(N_NODES);         // [zeroed]
    const size_t zero_words = woff;
    unsigned* binned = (unsigned*)ALLOC((size_t)NB2 * CAPG);
    unsigned short* h = (unsigned short*)ALLOC(NF / 2);
    float* s       = ALLOC(N_NODES);
    float* t       = ALLOC(N_NODES);
    float2* gb2    = (float2*)ALLOC(256 * 64 * 2);
    float* gnorm   = ALLOC(256);
    float* bnorm   = ALLOC(256);
    #undef ALLOC

    hipMemsetAsync(d_ws, 0, zero_words * sizeof(float), stream);

    k_pre<<<GRID_A, 256, 0, stream>>>(x, W, b, a, PE, Wg, Wb, bg, bb,
                                      edge, degree, idx,
                                      h, s, t, gb2, gnorm, bnorm,
                                      gcursor, binned, degsum, mult);
    k_mega<<<NB2, 256, 0, stream>>>(binned, gcursor, h, s, t, degree, degsum,
                                    Wadd, Wrev, gb2, mult, gnorm, bnorm,
                                    out, lacc, donecnt);
}

// Round 8
// 313.147 us; speedup vs baseline: 1.6498x; 1.6498x over previous
//
#include <hip/hip_runtime.h>
#include <math.h>

#define N_NODES 50000
#define E_EDGES 1600000
#define IN_F    128
#define OUT_F   64
#define OMEGA   0.1f
#define NIDX    5000
#define NB2     1563       // ceil(50000/32) buckets of 32 nodes
#define CAPG    1536       // fixed bucket capacity (mean 1024, +16 sigma)
#define SRT_SZ  1792       // CAPG + 32*7 pad headroom
#define ZROW    50000      // zeroed h row used by pad entries

#define GRID_B  98         // bin sub-blocks (16384 edges each) -- FIRST
#define GRID_H  782        // node_h sub-blocks (64 rows each)
#define GRID_G  64         // gamma sub-blocks (4 degrees each)
#define GRID_M  20         // mult/degsum sub-blocks
#define GRID_A  (GRID_B + GRID_H + GRID_G + GRID_M)
#define ACH     16384

typedef __attribute__((ext_vector_type(8))) short short8_t;
typedef __attribute__((ext_vector_type(4))) float f32x4;

__device__ __forceinline__ float lrelu(float x) { return x > 0.f ? x : 0.01f * x; }

__device__ __forceinline__ unsigned short f2bf(float f) {
    unsigned u = __float_as_uint(f);
    return (unsigned short)((u + 0x7FFFu + ((u >> 16) & 1u)) >> 16);
}
__device__ __forceinline__ float bf2f(unsigned short v) {
    return __uint_as_float((unsigned)v << 16);
}

// ============ K_pre: union of {bin | node_h | gamma | mult+degsum} ==========
__global__ __launch_bounds__(256) void k_pre(
    const float* __restrict__ x, const float* __restrict__ W,
    const float* __restrict__ b, const float* __restrict__ a,
    const float* __restrict__ PE, const float* __restrict__ Wg,
    const float* __restrict__ Wb, const float* __restrict__ bg,
    const float* __restrict__ bb,
    const int* __restrict__ edge, const int* __restrict__ degree,
    const int* __restrict__ idx,
    unsigned short* __restrict__ h, float* __restrict__ s, float* __restrict__ t,
    float2* __restrict__ gb2, float* __restrict__ gnorm, float* __restrict__ bnorm,
    int* __restrict__ gcursor, unsigned* __restrict__ binned,
    int* __restrict__ degsum, int* __restrict__ mult)
{
    __shared__ int sbuf_i[4352];               // 17408 B: xs (node_h) | hist+base (bin)
    const int blk = blockIdx.x;
    const int tid = threadIdx.x;
    const int lane = tid & 63, w = tid >> 6;

    if (blk < GRID_B) {
        // -------- bin: 2-pass LDS-aggregated bucket scatter (block-private runs)
        int* hist = sbuf_i;
        int* base = sbuf_i + NB2;
        for (int i = tid; i < NB2; i += 256) hist[i] = 0;
        __syncthreads();
        const int e0 = blk * ACH;
        const int e1 = min(e0 + ACH, E_EDGES);
        for (int e = e0 + tid; e < e1; e += 256) atomicAdd(&hist[edge[e] >> 5], 1);
        __syncthreads();
        for (int bk = tid; bk < NB2; bk += 256) {
            const int c = hist[bk];
            base[bk] = c ? atomicAdd(&gcursor[bk], c) : 0;
            hist[bk] = 0;
        }
        __syncthreads();
        for (int e = e0 + tid; e < e1; e += 256) {
            const int sv = edge[e];
            const int dvv = edge[E_EDGES + e];
            const int bk = sv >> 5;
            const int pos = base[bk] + atomicAdd(&hist[bk], 1);
            if (pos < CAPG)
                binned[(size_t)bk * CAPG + pos] = ((unsigned)(sv & 31) << 16) | (unsigned)dvv;
        }
    } else if (blk < GRID_B + GRID_H) {
        // -------- node_h: h = (x@W^T + b)*8 (bf16); s,t ----------------------
        unsigned short* xs = (unsigned short*)sbuf_i;   // [64][136]
        const int l15 = lane & 15, l4 = lane >> 4;
        const int row0 = (blk - GRID_B) * 64;

        short8_t bw_[4][4];
        #pragma unroll
        for (int nt = 0; nt < 4; ++nt) {
            #pragma unroll
            for (int ks = 0; ks < 4; ++ks) {
                const float* wp = &W[(nt * 16 + l15) * 128 + ks * 32 + l4 * 8];
                const float4 w0 = *(const float4*)wp;
                const float4 w1 = *(const float4*)(wp + 4);
                short8_t v;
                v[0] = (short)f2bf(w0.x); v[1] = (short)f2bf(w0.y);
                v[2] = (short)f2bf(w0.z); v[3] = (short)f2bf(w0.w);
                v[4] = (short)f2bf(w1.x); v[5] = (short)f2bf(w1.y);
                v[6] = (short)f2bf(w1.z); v[7] = (short)f2bf(w1.w);
                bw_[nt][ks] = v;
            }
        }
        float bcol[4], acol[4], acol2[4];
        #pragma unroll
        for (int nt = 0; nt < 4; ++nt) {
            bcol[nt]  = b[nt * 16 + l15];
            acol[nt]  = a[nt * 16 + l15];
            acol2[nt] = a[64 + nt * 16 + l15];
        }

        for (int f = tid; f < 2048; f += 256) {
            const int row = f >> 5, c4 = f & 31;
            const int rsrc = min(row0 + row, N_NODES - 1);
            const float4 v = *(const float4*)&x[(size_t)rsrc * IN_F + c4 * 4];
            ushort4 u;
            u.x = f2bf(v.x); u.y = f2bf(v.y); u.z = f2bf(v.z); u.w = f2bf(v.w);
            *(ushort4*)&xs[row * 136 + c4 * 4] = u;
        }
        __syncthreads();

        short8_t av[4];
        #pragma unroll
        for (int ks = 0; ks < 4; ++ks)
            av[ks] = *(const short8_t*)&xs[(w * 16 + l15) * 136 + ks * 32 + l4 * 8];

        f32x4 acc[4];
        #pragma unroll
        for (int nt = 0; nt < 4; ++nt) { acc[nt][0]=0.f; acc[nt][1]=0.f; acc[nt][2]=0.f; acc[nt][3]=0.f; }
        #pragma unroll
        for (int nt = 0; nt < 4; ++nt)
            #pragma unroll
            for (int ks = 0; ks < 4; ++ks)
                acc[nt] = __builtin_amdgcn_mfma_f32_16x16x32_bf16(av[ks], bw_[nt][ks], acc[nt], 0, 0, 0);

        float sp[4] = {0.f,0.f,0.f,0.f}, tp[4] = {0.f,0.f,0.f,0.f};
        #pragma unroll
        for (int nt = 0; nt < 4; ++nt) {
            #pragma unroll
            for (int reg = 0; reg < 4; ++reg) {
                const float hv = (acc[nt][reg] + bcol[nt]) * 8.0f;
                const int row = row0 + w * 16 + l4 * 4 + reg;
                if (row < N_NODES) h[(size_t)row * OUT_F + nt * 16 + l15] = f2bf(hv);
                sp[reg] = fmaf(hv, acol[nt],  sp[reg]);
                tp[reg] = fmaf(hv, acol2[nt], tp[reg]);
            }
        }
        #pragma unroll
        for (int reg = 0; reg < 4; ++reg) {
            float sv = sp[reg], tv = tp[reg];
            for (int m = 1; m < 16; m <<= 1) {
                sv += __shfl_xor(sv, m, 64);
                tv += __shfl_xor(tv, m, 64);
            }
            const int row = row0 + w * 16 + l4 * 4 + reg;
            if (l15 == 0 && row < N_NODES) { s[row] = sv; t[row] = tv; }
        }
    } else if (blk < GRID_B + GRID_H + GRID_G) {
        // -------- gamma/beta + norm tables (wave per degree) -----------------
        const int d = (blk - GRID_B - GRID_H) * 4 + w;
        const int o = lane;
        float ga = bg[o], be = bb[o];
        #pragma unroll 8
        for (int k = 0; k < 64; ++k) {
            const float m = PE[d * 64 + k];
            ga = fmaf(m, Wg[k * 64 + o], ga);
            be = fmaf(m, Wb[k * 64 + o], be);
        }
        ga = lrelu(ga); be = lrelu(be);
        gb2[d * 64 + o] = make_float2(ga, be);
        float g2 = ga * ga, b2 = be * be;
        for (int m2 = 32; m2; m2 >>= 1) {
            g2 += __shfl_down(g2, m2, 64);
            b2 += __shfl_down(b2, m2, 64);
        }
        if (o == 0) { gnorm[d] = sqrtf(g2); bnorm[d] = sqrtf(b2); }
    } else {
        // -------- mult histogram + degree sum + h zero-row -------------------
        const int b0 = blk - GRID_B - GRID_H - GRID_G;
        if (b0 == 0 && tid < 32) ((unsigned*)h)[(size_t)ZROW * 32 + tid] = 0u;
        const int stride = GRID_M * 256;
        for (int i2 = b0 * 256 + tid; i2 < NIDX; i2 += stride)
            atomicAdd(&mult[idx[i2]], 1);
        int dvs = 0;
        for (int i2 = b0 * 256 + tid; i2 < N_NODES; i2 += stride)
            dvs += degree[i2];
        for (int off = 32; off; off >>= 1) dvs += __shfl_down(dvs, off, 64);
        if (lane == 0 && dvs) atomicAdd(degsum, dvs);
    }
}

// ============ k_mega: reg-held sort + padded gather + MFMA + fused loss =====
__global__ __launch_bounds__(256, 4) void k_mega(
    const unsigned* __restrict__ binned, const int* __restrict__ gcursor,
    const unsigned short* __restrict__ h, const float* __restrict__ s,
    const float* __restrict__ t, const int* __restrict__ degree,
    const int* __restrict__ degsum,
    const float* __restrict__ Wadd, const float* __restrict__ Wrev,
    const float2* __restrict__ gb2,
    const int* __restrict__ mult, const float* __restrict__ gnorm,
    const float* __restrict__ bnorm,
    float* __restrict__ out, float* __restrict__ lacc,
    unsigned* __restrict__ donecnt)
{
    __shared__ unsigned srt[SRT_SZ];          // sorted (dst | ee_bf16<<16), 8-padded runs
    __shared__ unsigned short si16[32 * 72];  // i in bf16, stride 72
    __shared__ float hp_l[32 * 68];           // hp f32, stride 68
    __shared__ float rs_l[32], sv_l[32];
    __shared__ int deg_l[32], cnt[32], nbs[33], curs[32];

    const int tid = threadIdx.x;
    const int lane = tid & 63, w = tid >> 6;
    const int l15 = lane & 15, l4 = lane >> 4;
    const int mat = w >> 1, rt = w & 1;       // wave role: matrix, row-tile
    const int bkt = blockIdx.x, n0 = bkt * 32;

    // B-fragments of this wave's weight matrix
    const float* __restrict__ Wsel = mat ? Wrev : Wadd;
    short8_t bfr[4][2];
    #pragma unroll
    for (int nt = 0; nt < 4; ++nt) {
        #pragma unroll
        for (int ks = 0; ks < 2; ++ks) {
            const float* wp = &Wsel[(nt * 16 + l15) * 64 + ks * 32 + l4 * 8];
            const float4 w0 = *(const float4*)wp;
            const float4 w1 = *(const float4*)(wp + 4);
            short8_t v;
            v[0] = (short)f2bf(w0.x); v[1] = (short)f2bf(w0.y);
            v[2] = (short)f2bf(w0.z); v[3] = (short)f2bf(w0.w);
            v[4] = (short)f2bf(w1.x); v[5] = (short)f2bf(w1.y);
            v[6] = (short)f2bf(w1.z); v[7] = (short)f2bf(w1.w);
            bfr[nt][ks] = v;
        }
    }

    if (tid < 32) {
        cnt[tid] = 0;
        const int nd = n0 + tid;
        sv_l[tid]  = (nd < N_NODES) ? s[nd] : 0.f;
        deg_l[tid] = (nd < N_NODES) ? degree[nd] : 0;
    }
    __syncthreads();

    const int cntE = min(gcursor[bkt], CAPG);
    const size_t bb = (size_t)bkt * CAPG;

    // single global read of this bucket's entries into registers
    unsigned ent[6];
    #pragma unroll
    for (int k = 0; k < 6; ++k) {
        const int j = k * 256 + tid;
        ent[k] = (j < cntE) ? binned[bb + j] : 0xFFFFFFFFu;
    }
    // pass 1: per-node histogram (from regs)
    #pragma unroll
    for (int k = 0; k < 6; ++k)
        if (ent[k] != 0xFFFFFFFFu) atomicAdd(&cnt[ent[k] >> 16], 1);
    __syncthreads();
    // scan of 8-padded counts
    if (tid < 32) {
        const int pv = (cnt[tid] + 7) & ~7;
        int val = pv;
        #pragma unroll
        for (int m = 1; m < 32; m <<= 1) {
            const int o = __shfl_up(val, m, 64);
            if (tid >= m) val += o;
        }
        nbs[tid] = val - pv;
        curs[tid] = val - pv;
        if (tid == 31) nbs[32] = val;
    }
    __syncthreads();
    // fill pad slots (dst=ZROW, ee=0) — disjoint from sort positions
    if (tid < 32) {
        const int p0 = nbs[tid] + cnt[tid], p1 = nbs[tid + 1];
        for (int p = p0; p < p1; ++p) srt[p] = (unsigned)ZROW;
    }
    // pass 2: ee + counting-sort into LDS (from regs)
    #pragma unroll
    for (int k = 0; k < 6; ++k) {
        const unsigned en = ent[k];
        if (en != 0xFFFFFFFFu) {
            const int sl = en >> 16;
            const int dvv = en & 0xFFFF;
            const float z = sv_l[sl] + t[dvv];
            const float ee = __expf(-(z > 0.f ? z : 0.01f * z));
            const int p = atomicAdd(&curs[sl], 1);
            srt[p] = (unsigned)dvv | ((unsigned)f2bf(ee) << 16);
        }
    }
    __syncthreads();

    // gather: wave w -> nodes w, w+4, ...; 8-edge-parallel, guard-free (padded)
    const int g = lane >> 3, ql = lane & 7;
    for (int nl = w; nl < 32; nl += 4) {
        const int rb = nbs[nl], re = nbs[nl + 1];
        float ag[8] = {0.f,0.f,0.f,0.f,0.f,0.f,0.f,0.f};
        float pp[8] = {0.f,0.f,0.f,0.f,0.f,0.f,0.f,0.f};
        float er = 0.f;
        #pragma unroll 2
        for (int st = rb; st < re; st += 8) {
            const unsigned en = srt[st + g];
            const float ee = bf2f((unsigned short)(en >> 16));
            const int dvv = en & 0xFFFF;
            const short8_t hv = *(const short8_t*)(h + (size_t)dvv * OUT_F + ql * 8);
            er += ee;
            #pragma unroll
            for (int c = 0; c < 8; ++c) {
                const float f = bf2f((unsigned short)hv[c]);
                ag[c] += f;
                pp[c] = fmaf(ee, f, pp[c]);
            }
        }
        #pragma unroll
        for (int c = 0; c < 8; ++c) {
            ag[c] += __shfl_xor(ag[c], 8, 64);
            ag[c] += __shfl_xor(ag[c], 16, 64);
            ag[c] += __shfl_xor(ag[c], 32, 64);
            pp[c] += __shfl_xor(pp[c], 8, 64);
            pp[c] += __shfl_xor(pp[c], 16, 64);
            pp[c] += __shfl_xor(pp[c], 32, 64);
        }
        er += __shfl_xor(er, 8, 64);
        er += __shfl_xor(er, 16, 64);
        er += __shfl_xor(er, 32, 64);
        if (lane == 0) rs_l[nl] = er;
        if (lane < 8) {
            const int dg = deg_l[nl];
            const float inv = (dg > 0) ? 1.f / (float)dg : 0.f;
            short8_t iv;
            #pragma unroll
            for (int c = 0; c < 8; ++c) iv[c] = (short)f2bf(ag[c] * inv);
            *(short8_t*)&si16[nl * 72 + lane * 8] = iv;
            float4 h0; h0.x = pp[0]; h0.y = pp[1]; h0.z = pp[2]; h0.w = pp[3];
            float4 h1; h1.x = pp[4]; h1.y = pp[5]; h1.z = pp[6]; h1.w = pp[7];
            *(float4*)&hp_l[nl * 68 + lane * 8]     = h0;
            *(float4*)&hp_l[nl * 68 + lane * 8 + 4] = h1;
        }
    }
    __syncthreads();

    // MFMA: b_sel = i @ Wsel^T for this wave's 16 rows
    short8_t av[2];
    #pragma unroll
    for (int ks = 0; ks < 2; ++ks)
        av[ks] = *(const short8_t*)&si16[(rt * 16 + l15) * 72 + ks * 32 + l4 * 8];
    f32x4 acc[4];
    #pragma unroll
    for (int nt = 0; nt < 4; ++nt) { acc[nt][0]=0.f; acc[nt][1]=0.f; acc[nt][2]=0.f; acc[nt][3]=0.f; }
    #pragma unroll
    for (int nt = 0; nt < 4; ++nt)
        #pragma unroll
        for (int ks = 0; ks < 2; ++ks)
            acc[nt] = __builtin_amdgcn_mfma_f32_16x16x32_bf16(av[ks], bfr[nt][ks], acc[nt], 0, 0, 0);

    const float kthr = (float)(*degsum) / (float)N_NODES;   // K_MULT = 1

    float lbacc = 0.f, lfacc = 0.f;
    #pragma unroll
    for (int reg = 0; reg < 4; ++reg) {
        const int nl = rt * 16 + l4 * 4 + reg;
        const int node = n0 + nl;
        const bool valid = node < N_NODES;
        const int dg = deg_l[nl];
        const bool rfl = ((float)dg < kthr);           // R == 1
        const bool sel = (rfl == (mat == 0)) && valid;
        const float rdenom = 1.f / (rs_l[nl] + 1e-5f + 1.f);
        const float sgn = (mat == 0) ? OMEGA : -OMEGA;
        float sq = 0.f;
        #pragma unroll
        for (int nt = 0; nt < 4; ++nt) {
            const int o = nt * 16 + l15;
            const float ad = acc[nt][reg];
            const float2 gb = gb2[dg * 64 + o];
            const float bs = fmaf(gb.x + 1.f, ad, gb.y);
            sq = fmaf(bs, bs, sq);
            if (sel) {
                float ov = (hp_l[nl * 68 + o] + sgn * bs) * rdenom;
                ov = ov > 0.f ? ov : 0.01f * ov;
                out[(size_t)node * OUT_F + o] = ov;
            }
        }
        sq += __shfl_xor(sq, 1, 64);
        sq += __shfl_xor(sq, 2, 64);
        sq += __shfl_xor(sq, 4, 64);
        sq += __shfl_xor(sq, 8, 64);
        if (l15 == 0 && sel) {
            const int mlt = mult[node];
            if (mlt) {
                lbacc += (float)mlt * sqrtf(sq);
                lfacc += (float)mlt * (gnorm[dg] + bnorm[dg]);
            }
        }
    }
    lbacc += __shfl_xor(lbacc, 16, 64);
    lbacc += __shfl_xor(lbacc, 32, 64);
    lfacc += __shfl_xor(lfacc, 16, 64);
    lfacc += __shfl_xor(lfacc, 32, 64);
    if (lane == 0 && (lbacc != 0.f || lfacc != 0.f)) {
        atomicAdd(&lacc[0], lbacc);
        atomicAdd(&lacc[1], lfacc);
    }
    __syncthreads();
    if (tid == 0) {
        __threadfence();
        const unsigned prev = atomicAdd(donecnt, 1u);
        if (prev == (unsigned)gridDim.x - 1) {
            const float tb = atomicAdd(&lacc[0], 0.f);
            const float tf = atomicAdd(&lacc[1], 0.f);
            out[(size_t)N_NODES * OUT_F]     = tb / (float)NIDX;
            out[(size_t)N_NODES * OUT_F + 1] = tf / (float)NIDX;
        }
    }
}

extern "C" void kernel_launch(void* const* d_in, const int* in_sizes, int n_in,
                              void* d_out, int out_size, void* d_ws, size_t ws_size,
                              hipStream_t stream)
{
    const float* x    = (const float*)d_in[0];
    const float* W    = (const float*)d_in[1];
    const float* b    = (const float*)d_in[2];
    const float* a    = (const float*)d_in[3];
    const float* Wg   = (const float*)d_in[4];
    const float* Wb   = (const float*)d_in[5];
    const float* bg   = (const float*)d_in[6];
    const float* bb   = (const float*)d_in[7];
    const float* Wadd = (const float*)d_in[8];
    const float* Wrev = (const float*)d_in[9];
    const float* PE   = (const float*)d_in[10];
    const int*  edge   = (const int*)d_in[11];
    const int*  degree = (const int*)d_in[12];
    const int*  idx    = (const int*)d_in[13];
    float* out = (float*)d_out;

    // ---- workspace layout: zero-init arrays FIRST (one memset) ----
    float* ws = (float*)d_ws;
    size_t woff = 0;
    #define ALLOC(nwords) (ws + woff); woff += (((size_t)(nwords)) + 3) & ~(size_t)3;
    int*   gcursor = (int*)ALLOC(NB2);             // [zeroed]
    int*   degsum  = (int*)ALLOC(4);               // [zeroed]
    float* lacc    = ALLOC(4);                     // [zeroed]
    unsigned* donecnt = (unsigned*)ALLOC(4);       // [zeroed]
    int*   mult    = (int*)ALLOC(N_NODES);         // [zeroed]
    const size_t zero_words = woff;
    unsigned* binned = (unsigned*)ALLOC((size_t)NB2 * CAPG);
    unsigned short* h = (unsigned short*)ALLOC(((size_t)(N_NODES + 8) * OUT_F) / 2);
    float* s       = ALLOC(N_NODES);
    float* t       = ALLOC(N_NODES);
    float2* gb2    = (float2*)ALLOC(256 * 64 * 2);
    float* gnorm   = ALLOC(256);
    float* bnorm   = ALLOC(256);
    #undef ALLOC

    hipMemsetAsync(d_ws, 0, zero_words * sizeof(float), stream);

    k_pre<<<GRID_A, 256, 0, stream>>>(x, W, b, a, PE, Wg, Wb, bg, bb,
                                      edge, degree, idx,
                                      h, s, t, gb2, gnorm, bnorm,
                                      gcursor, binned, degsum, mult);
    k_mega<<<NB2, 256, 0, stream>>>(binned, gcursor, h, s, t, degree, degsum,
                                    Wadd, Wrev, gb2, mult, gnorm, bnorm,
                                    out, lacc, donecnt);
}

// Round 9
// 298.232 us; speedup vs baseline: 1.7323x; 1.0500x over previous
//
#include <hip/hip_runtime.h>
#include <math.h>

#define N_NODES 50000
#define E_EDGES 1600000
#define IN_F    128
#define OUT_F   64
#define OMEGA   0.1f
#define NIDX    5000
#define NB2     1563       // ceil(50000/32) buckets of 32 nodes
#define CAPG    1536       // fixed bucket capacity (mean 1024, +16 sigma)
#define SRT_SZ  1792       // CAPG + 32*7 pad headroom
#define ZROW    50000      // zeroed h row used by pad entries

#define GRID_B  98         // bin sub-blocks (16384 edges each) -- FIRST
#define GRID_H  782        // node_h sub-blocks (64 rows each)
#define GRID_G  64         // gamma sub-blocks (4 degrees each)
#define GRID_M  20         // mult/degsum sub-blocks
#define GRID_A  (GRID_B + GRID_H + GRID_G + GRID_M)
#define ACH     16384

typedef __attribute__((ext_vector_type(8))) short short8_t;
typedef __attribute__((ext_vector_type(4))) float f32x4;

__device__ __forceinline__ float lrelu(float x) { return x > 0.f ? x : 0.01f * x; }

__device__ __forceinline__ unsigned short f2bf(float f) {
    unsigned u = __float_as_uint(f);
    return (unsigned short)((u + 0x7FFFu + ((u >> 16) & 1u)) >> 16);
}
__device__ __forceinline__ float bf2f(unsigned short v) {
    return __uint_as_float((unsigned)v << 16);
}

// ============ K_pre: union of {bin | node_h | gamma | mult+degsum} ==========
__global__ __launch_bounds__(256) void k_pre(
    const float* __restrict__ x, const float* __restrict__ W,
    const float* __restrict__ b, const float* __restrict__ a,
    const float* __restrict__ PE, const float* __restrict__ Wg,
    const float* __restrict__ Wb, const float* __restrict__ bg,
    const float* __restrict__ bb,
    const int* __restrict__ edge, const int* __restrict__ degree,
    const int* __restrict__ idx,
    unsigned short* __restrict__ h, float* __restrict__ s, float* __restrict__ t,
    float2* __restrict__ gb2, float* __restrict__ gnorm, float* __restrict__ bnorm,
    int* __restrict__ gcursor, unsigned* __restrict__ binned,
    int* __restrict__ degsum, int* __restrict__ mult)
{
    __shared__ int sbuf_i[4352];               // 17408 B: xs (node_h) | hist+base (bin)
    const int blk = blockIdx.x;
    const int tid = threadIdx.x;
    const int lane = tid & 63, w = tid >> 6;

    if (blk < GRID_B) {
        // -------- bin: 2-pass LDS-aggregated bucket scatter (block-private runs)
        int* hist = sbuf_i;
        int* base = sbuf_i + NB2;
        for (int i = tid; i < NB2; i += 256) hist[i] = 0;
        __syncthreads();
        const int e0 = blk * ACH;
        const int e1 = min(e0 + ACH, E_EDGES);
        for (int e = e0 + tid; e < e1; e += 256) atomicAdd(&hist[edge[e] >> 5], 1);
        __syncthreads();
        for (int bk = tid; bk < NB2; bk += 256) {
            const int c = hist[bk];
            base[bk] = c ? atomicAdd(&gcursor[bk], c) : 0;
            hist[bk] = 0;
        }
        __syncthreads();
        for (int e = e0 + tid; e < e1; e += 256) {
            const int sv = edge[e];
            const int dvv = edge[E_EDGES + e];
            const int bk = sv >> 5;
            const int pos = base[bk] + atomicAdd(&hist[bk], 1);
            if (pos < CAPG)
                binned[(size_t)bk * CAPG + pos] = ((unsigned)(sv & 31) << 16) | (unsigned)dvv;
        }
    } else if (blk < GRID_B + GRID_H) {
        // -------- node_h: h = (x@W^T + b)*8 (bf16); s,t ----------------------
        unsigned short* xs = (unsigned short*)sbuf_i;   // [64][136]
        const int l15 = lane & 15, l4 = lane >> 4;
        const int row0 = (blk - GRID_B) * 64;

        short8_t bw_[4][4];
        #pragma unroll
        for (int nt = 0; nt < 4; ++nt) {
            #pragma unroll
            for (int ks = 0; ks < 4; ++ks) {
                const float* wp = &W[(nt * 16 + l15) * 128 + ks * 32 + l4 * 8];
                const float4 w0 = *(const float4*)wp;
                const float4 w1 = *(const float4*)(wp + 4);
                short8_t v;
                v[0] = (short)f2bf(w0.x); v[1] = (short)f2bf(w0.y);
                v[2] = (short)f2bf(w0.z); v[3] = (short)f2bf(w0.w);
                v[4] = (short)f2bf(w1.x); v[5] = (short)f2bf(w1.y);
                v[6] = (short)f2bf(w1.z); v[7] = (short)f2bf(w1.w);
                bw_[nt][ks] = v;
            }
        }
        float bcol[4], acol[4], acol2[4];
        #pragma unroll
        for (int nt = 0; nt < 4; ++nt) {
            bcol[nt]  = b[nt * 16 + l15];
            acol[nt]  = a[nt * 16 + l15];
            acol2[nt] = a[64 + nt * 16 + l15];
        }

        for (int f = tid; f < 2048; f += 256) {
            const int row = f >> 5, c4 = f & 31;
            const int rsrc = min(row0 + row, N_NODES - 1);
            const float4 v = *(const float4*)&x[(size_t)rsrc * IN_F + c4 * 4];
            ushort4 u;
            u.x = f2bf(v.x); u.y = f2bf(v.y); u.z = f2bf(v.z); u.w = f2bf(v.w);
            *(ushort4*)&xs[row * 136 + c4 * 4] = u;
        }
        __syncthreads();

        short8_t av[4];
        #pragma unroll
        for (int ks = 0; ks < 4; ++ks)
            av[ks] = *(const short8_t*)&xs[(w * 16 + l15) * 136 + ks * 32 + l4 * 8];

        f32x4 acc[4];
        #pragma unroll
        for (int nt = 0; nt < 4; ++nt) { acc[nt][0]=0.f; acc[nt][1]=0.f; acc[nt][2]=0.f; acc[nt][3]=0.f; }
        #pragma unroll
        for (int nt = 0; nt < 4; ++nt)
            #pragma unroll
            for (int ks = 0; ks < 4; ++ks)
                acc[nt] = __builtin_amdgcn_mfma_f32_16x16x32_bf16(av[ks], bw_[nt][ks], acc[nt], 0, 0, 0);

        float sp[4] = {0.f,0.f,0.f,0.f}, tp[4] = {0.f,0.f,0.f,0.f};
        #pragma unroll
        for (int nt = 0; nt < 4; ++nt) {
            #pragma unroll
            for (int reg = 0; reg < 4; ++reg) {
                const float hv = (acc[nt][reg] + bcol[nt]) * 8.0f;
                const int row = row0 + w * 16 + l4 * 4 + reg;
                if (row < N_NODES) h[(size_t)row * OUT_F + nt * 16 + l15] = f2bf(hv);
                sp[reg] = fmaf(hv, acol[nt],  sp[reg]);
                tp[reg] = fmaf(hv, acol2[nt], tp[reg]);
            }
        }
        #pragma unroll
        for (int reg = 0; reg < 4; ++reg) {
            float sv = sp[reg], tv = tp[reg];
            for (int m = 1; m < 16; m <<= 1) {
                sv += __shfl_xor(sv, m, 64);
                tv += __shfl_xor(tv, m, 64);
            }
            const int row = row0 + w * 16 + l4 * 4 + reg;
            if (l15 == 0 && row < N_NODES) { s[row] = sv; t[row] = tv; }
        }
    } else if (blk < GRID_B + GRID_H + GRID_G) {
        // -------- gamma/beta + norm tables (wave per degree) -----------------
        const int d = (blk - GRID_B - GRID_H) * 4 + w;
        const int o = lane;
        float ga = bg[o], be = bb[o];
        #pragma unroll 8
        for (int k = 0; k < 64; ++k) {
            const float m = PE[d * 64 + k];
            ga = fmaf(m, Wg[k * 64 + o], ga);
            be = fmaf(m, Wb[k * 64 + o], be);
        }
        ga = lrelu(ga); be = lrelu(be);
        gb2[d * 64 + o] = make_float2(ga, be);
        float g2 = ga * ga, b2 = be * be;
        for (int m2 = 32; m2; m2 >>= 1) {
            g2 += __shfl_down(g2, m2, 64);
            b2 += __shfl_down(b2, m2, 64);
        }
        if (o == 0) { gnorm[d] = sqrtf(g2); bnorm[d] = sqrtf(b2); }
    } else {
        // -------- mult histogram + degree sum + h zero-row -------------------
        const int b0 = blk - GRID_B - GRID_H - GRID_G;
        if (b0 == 0 && tid < 32) ((unsigned*)h)[(size_t)ZROW * 32 + tid] = 0u;
        const int stride = GRID_M * 256;
        for (int i2 = b0 * 256 + tid; i2 < NIDX; i2 += stride)
            atomicAdd(&mult[idx[i2]], 1);
        int dvs = 0;
        for (int i2 = b0 * 256 + tid; i2 < N_NODES; i2 += stride)
            dvs += degree[i2];
        for (int off = 32; off; off >>= 1) dvs += __shfl_down(dvs, off, 64);
        if (lane == 0 && dvs) atomicAdd(degsum, dvs);
    }
}

// ============ k_mega: reg-held sort + padded gather + MFMA + loss atomics ===
__global__ __launch_bounds__(256, 4) void k_mega(
    const unsigned* __restrict__ binned, const int* __restrict__ gcursor,
    const unsigned short* __restrict__ h, const float* __restrict__ s,
    const float* __restrict__ t, const int* __restrict__ degree,
    const int* __restrict__ degsum,
    const float* __restrict__ Wadd, const float* __restrict__ Wrev,
    const float2* __restrict__ gb2,
    const int* __restrict__ mult, const float* __restrict__ gnorm,
    const float* __restrict__ bnorm,
    float* __restrict__ out, float* __restrict__ lacc)
{
    __shared__ unsigned srt[SRT_SZ];          // sorted (dst | ee_bf16<<16), 8-padded runs
    __shared__ unsigned short si16[32 * 72];  // i in bf16, stride 72
    __shared__ float hp_l[32 * 68];           // hp f32, stride 68
    __shared__ float rs_l[32], sv_l[32];
    __shared__ int deg_l[32], cnt[32], nbs[33], curs[32];

    const int tid = threadIdx.x;
    const int lane = tid & 63, w = tid >> 6;
    const int l15 = lane & 15, l4 = lane >> 4;
    const int mat = w >> 1, rt = w & 1;       // wave role: matrix, row-tile
    const int bkt = blockIdx.x, n0 = bkt * 32;

    // B-fragments of this wave's weight matrix
    const float* __restrict__ Wsel = mat ? Wrev : Wadd;
    short8_t bfr[4][2];
    #pragma unroll
    for (int nt = 0; nt < 4; ++nt) {
        #pragma unroll
        for (int ks = 0; ks < 2; ++ks) {
            const float* wp = &Wsel[(nt * 16 + l15) * 64 + ks * 32 + l4 * 8];
            const float4 w0 = *(const float4*)wp;
            const float4 w1 = *(const float4*)(wp + 4);
            short8_t v;
            v[0] = (short)f2bf(w0.x); v[1] = (short)f2bf(w0.y);
            v[2] = (short)f2bf(w0.z); v[3] = (short)f2bf(w0.w);
            v[4] = (short)f2bf(w1.x); v[5] = (short)f2bf(w1.y);
            v[6] = (short)f2bf(w1.z); v[7] = (short)f2bf(w1.w);
            bfr[nt][ks] = v;
        }
    }

    if (tid < 32) {
        cnt[tid] = 0;
        const int nd = n0 + tid;
        sv_l[tid]  = (nd < N_NODES) ? s[nd] : 0.f;
        deg_l[tid] = (nd < N_NODES) ? degree[nd] : 0;
    }
    __syncthreads();

    const int cntE = min(gcursor[bkt], CAPG);
    const size_t bb = (size_t)bkt * CAPG;

    // single global read of this bucket's entries into registers
    unsigned ent[6];
    #pragma unroll
    for (int k = 0; k < 6; ++k) {
        const int j = k * 256 + tid;
        ent[k] = (j < cntE) ? binned[bb + j] : 0xFFFFFFFFu;
    }
    // pass 1: per-node histogram (from regs)
    #pragma unroll
    for (int k = 0; k < 6; ++k)
        if (ent[k] != 0xFFFFFFFFu) atomicAdd(&cnt[ent[k] >> 16], 1);
    __syncthreads();
    // scan of 8-padded counts
    if (tid < 32) {
        const int pv = (cnt[tid] + 7) & ~7;
        int val = pv;
        #pragma unroll
        for (int m = 1; m < 32; m <<= 1) {
            const int o = __shfl_up(val, m, 64);
            if (tid >= m) val += o;
        }
        nbs[tid] = val - pv;
        curs[tid] = val - pv;
        if (tid == 31) nbs[32] = val;
    }
    __syncthreads();
    // fill pad slots (dst=ZROW, ee=0) — disjoint from sort positions
    if (tid < 32) {
        const int p0 = nbs[tid] + cnt[tid], p1 = nbs[tid + 1];
        for (int p = p0; p < p1; ++p) srt[p] = (unsigned)ZROW;
    }
    // pass 2: ee + counting-sort into LDS (from regs)
    #pragma unroll
    for (int k = 0; k < 6; ++k) {
        const unsigned en = ent[k];
        if (en != 0xFFFFFFFFu) {
            const int sl = en >> 16;
            const int dvv = en & 0xFFFF;
            const float z = sv_l[sl] + t[dvv];
            const float ee = __expf(-(z > 0.f ? z : 0.01f * z));
            const int p = atomicAdd(&curs[sl], 1);
            srt[p] = (unsigned)dvv | ((unsigned)f2bf(ee) << 16);
        }
    }
    __syncthreads();

    // gather: wave w -> nodes w, w+4, ...; 8-edge-parallel, guard-free (padded)
    const int g = lane >> 3, ql = lane & 7;
    for (int nl = w; nl < 32; nl += 4) {
        const int rb = nbs[nl], re = nbs[nl + 1];
        float ag[8] = {0.f,0.f,0.f,0.f,0.f,0.f,0.f,0.f};
        float pp[8] = {0.f,0.f,0.f,0.f,0.f,0.f,0.f,0.f};
        float er = 0.f;
        #pragma unroll 2
        for (int st = rb; st < re; st += 8) {
            const unsigned en = srt[st + g];
            const float ee = bf2f((unsigned short)(en >> 16));
            const int dvv = en & 0xFFFF;
            const short8_t hv = *(const short8_t*)(h + (size_t)dvv * OUT_F + ql * 8);
            er += ee;
            #pragma unroll
            for (int c = 0; c < 8; ++c) {
                const float f = bf2f((unsigned short)hv[c]);
                ag[c] += f;
                pp[c] = fmaf(ee, f, pp[c]);
            }
        }
        #pragma unroll
        for (int c = 0; c < 8; ++c) {
            ag[c] += __shfl_xor(ag[c], 8, 64);
            ag[c] += __shfl_xor(ag[c], 16, 64);
            ag[c] += __shfl_xor(ag[c], 32, 64);
            pp[c] += __shfl_xor(pp[c], 8, 64);
            pp[c] += __shfl_xor(pp[c], 16, 64);
            pp[c] += __shfl_xor(pp[c], 32, 64);
        }
        er += __shfl_xor(er, 8, 64);
        er += __shfl_xor(er, 16, 64);
        er += __shfl_xor(er, 32, 64);
        if (lane == 0) rs_l[nl] = er;
        if (lane < 8) {
            const int dg = deg_l[nl];
            const float inv = (dg > 0) ? 1.f / (float)dg : 0.f;
            short8_t iv;
            #pragma unroll
            for (int c = 0; c < 8; ++c) iv[c] = (short)f2bf(ag[c] * inv);
            *(short8_t*)&si16[nl * 72 + lane * 8] = iv;
            float4 h0; h0.x = pp[0]; h0.y = pp[1]; h0.z = pp[2]; h0.w = pp[3];
            float4 h1; h1.x = pp[4]; h1.y = pp[5]; h1.z = pp[6]; h1.w = pp[7];
            *(float4*)&hp_l[nl * 68 + lane * 8]     = h0;
            *(float4*)&hp_l[nl * 68 + lane * 8 + 4] = h1;
        }
    }
    __syncthreads();

    // MFMA: b_sel = i @ Wsel^T for this wave's 16 rows
    short8_t av[2];
    #pragma unroll
    for (int ks = 0; ks < 2; ++ks)
        av[ks] = *(const short8_t*)&si16[(rt * 16 + l15) * 72 + ks * 32 + l4 * 8];
    f32x4 acc[4];
    #pragma unroll
    for (int nt = 0; nt < 4; ++nt) { acc[nt][0]=0.f; acc[nt][1]=0.f; acc[nt][2]=0.f; acc[nt][3]=0.f; }
    #pragma unroll
    for (int nt = 0; nt < 4; ++nt)
        #pragma unroll
        for (int ks = 0; ks < 2; ++ks)
            acc[nt] = __builtin_amdgcn_mfma_f32_16x16x32_bf16(av[ks], bfr[nt][ks], acc[nt], 0, 0, 0);

    const float kthr = (float)(*degsum) / (float)N_NODES;   // K_MULT = 1

    float lbacc = 0.f, lfacc = 0.f;
    #pragma unroll
    for (int reg = 0; reg < 4; ++reg) {
        const int nl = rt * 16 + l4 * 4 + reg;
        const int node = n0 + nl;
        const bool valid = node < N_NODES;
        const int dg = deg_l[nl];
        const bool rfl = ((float)dg < kthr);           // R == 1
        const bool sel = (rfl == (mat == 0)) && valid;
        const float rdenom = 1.f / (rs_l[nl] + 1e-5f + 1.f);
        const float sgn = (mat == 0) ? OMEGA : -OMEGA;
        float sq = 0.f;
        #pragma unroll
        for (int nt = 0; nt < 4; ++nt) {
            const int o = nt * 16 + l15;
            const float ad = acc[nt][reg];
            const float2 gb = gb2[dg * 64 + o];
            const float bs = fmaf(gb.x + 1.f, ad, gb.y);
            sq = fmaf(bs, bs, sq);
            if (sel) {
                float ov = (hp_l[nl * 68 + o] + sgn * bs) * rdenom;
                ov = ov > 0.f ? ov : 0.01f * ov;
                out[(size_t)node * OUT_F + o] = ov;
            }
        }
        sq += __shfl_xor(sq, 1, 64);
        sq += __shfl_xor(sq, 2, 64);
        sq += __shfl_xor(sq, 4, 64);
        sq += __shfl_xor(sq, 8, 64);
        if (l15 == 0 && sel) {
            const int mlt = mult[node];
            if (mlt) {
                lbacc += (float)mlt * sqrtf(sq);
                lfacc += (float)mlt * (gnorm[dg] + bnorm[dg]);
            }
        }
    }
    lbacc += __shfl_xor(lbacc, 16, 64);
    lbacc += __shfl_xor(lbacc, 32, 64);
    lfacc += __shfl_xor(lfacc, 16, 64);
    lfacc += __shfl_xor(lfacc, 32, 64);
    if (lane == 0 && (lbacc != 0.f || lfacc != 0.f)) {
        atomicAdd(&lacc[0], lbacc);
        atomicAdd(&lacc[1], lfacc);
    }
    // NO __threadfence / donecnt: agent-scope fence = L2 writeback+invalidate on
    // gfx950 (non-coherent XCD L2s) -> evicted the whole working set (r8: +36MB
    // FETCH, +66us). Final scalars written by k_fin after kernel boundary.
}

// ============ k_fin: write the two loss scalars =============================
__global__ __launch_bounds__(64) void k_fin(const float* __restrict__ lacc,
                                            float* __restrict__ out)
{
    if (threadIdx.x == 0) {
        out[(size_t)N_NODES * OUT_F]     = lacc[0] * (1.0f / (float)NIDX);
        out[(size_t)N_NODES * OUT_F + 1] = lacc[1] * (1.0f / (float)NIDX);
    }
}

extern "C" void kernel_launch(void* const* d_in, const int* in_sizes, int n_in,
                              void* d_out, int out_size, void* d_ws, size_t ws_size,
                              hipStream_t stream)
{
    const float* x    = (const float*)d_in[0];
    const float* W    = (const float*)d_in[1];
    const float* b    = (const float*)d_in[2];
    const float* a    = (const float*)d_in[3];
    const float* Wg   = (const float*)d_in[4];
    const float* Wb   = (const float*)d_in[5];
    const float* bg   = (const float*)d_in[6];
    const float* bb   = (const float*)d_in[7];
    const float* Wadd = (const float*)d_in[8];
    const float* Wrev = (const float*)d_in[9];
    const float* PE   = (const float*)d_in[10];
    const int*  edge   = (const int*)d_in[11];
    const int*  degree = (const int*)d_in[12];
    const int*  idx    = (const int*)d_in[13];
    float* out = (float*)d_out;

    // ---- workspace layout: zero-init arrays FIRST (one memset) ----
    float* ws = (float*)d_ws;
    size_t woff = 0;
    #define ALLOC(nwords) (ws + woff); woff += (((size_t)(nwords)) + 3) & ~(size_t)3;
    int*   gcursor = (int*)ALLOC(NB2);             // [zeroed]
    int*   degsum  = (int*)ALLOC(4);               // [zeroed]
    float* lacc    = ALLOC(4);                     // [zeroed]
    int*   mult    = (int*)ALLOC(N_NODES);         // [zeroed]
    const size_t zero_words = woff;
    unsigned* binned = (unsigned*)ALLOC((size_t)NB2 * CAPG);
    unsigned short* h = (unsigned short*)ALLOC(((size_t)(N_NODES + 8) * OUT_F) / 2);
    float* s       = ALLOC(N_NODES);
    float* t       = ALLOC(N_NODES);
    float2* gb2    = (float2*)ALLOC(256 * 64 * 2);
    float* gnorm   = ALLOC(256);
    float* bnorm   = ALLOC(256);
    #undef ALLOC

    hipMemsetAsync(d_ws, 0, zero_words * sizeof(float), stream);

    k_pre<<<GRID_A, 256, 0, stream>>>(x, W, b, a, PE, Wg, Wb, bg, bb,
                                      edge, degree, idx,
                                      h, s, t, gb2, gnorm, bnorm,
                                      gcursor, binned, degsum, mult);
    k_mega<<<NB2, 256, 0, stream>>>(binned, gcursor, h, s, t, degree, degsum,
                                    Wadd, Wrev, gb2, mult, gnorm, bnorm,
                                    out, lacc);
    k_fin<<<1, 64, 0, stream>>>(lacc, out);
}